// Round 7
// baseline (173.194 us; speedup 1.0000x reference)
//
#include <hip/hip_runtime.h>
#include <cstdint>
#include <cstddef>

// RNNT joiner: logits[b,t,u,v] = sum_j tanh(E[b,t,j]+P[b,u,j]) * out_w[v,j] + out_b[v]
// B=4 T=256 U=64 D=512 J=640 V=1024.  M = 65536 rows (b,t,u), N=1024, K=640.
//
// ws layout (Z-path):
//   E  : bf16 [1024][640]             @ 0          (1,310,720 B)
//   P  : bf16 [ 256][640]             @ 1,310,720  (  327,680 B)
//   Wb : bf16 blocked [4][20][8192]   @ 1,638,400  (1,310,720 B)  pre-swizzled 256x32 tiles
//   Z  : bf16 blocked [256][20][8192] @ 2,949,120  (83,886,080 B) pre-swizzled 256x32 tiles
// total 86,835,200 B.  ws_size smaller -> fused fallback (R5 structure, 128x64 Wb blocks).

typedef __attribute__((ext_vector_type(8))) __bf16 bf16x8;
typedef __attribute__((ext_vector_type(4))) float f32x4;

// --- swizzle for [R][64] bf16 tiles (row stride 128B), used by fallback/proj ---
__device__ __forceinline__ int swz64(int row, int kElem) {
  return (row << 6) + (kElem ^ ((row & 7) << 3));
}
// --- swizzle for [R][32] bf16 tiles (row stride 64B): 16B chunk cc -> cc ^ ((row>>2)&3).
// Involution; spreads 16-row column-groups over 8 bank-pairs (2-way = free).
__device__ __forceinline__ int swz32(int row, int kElem) {
  return (row << 5) + ((kElem & 7) | (((kElem >> 3) ^ ((row >> 2) & 3)) << 3));
}

__device__ __forceinline__ float fast_tanh(float x) {
  float e = __builtin_amdgcn_exp2f(x * 2.88539008177793f);  // e^(2x)
  return 1.0f - 2.0f * __builtin_amdgcn_rcpf(e + 1.0f);
}

__device__ __forceinline__ void gload_lds16(const void* g, void* l) {
  __builtin_amdgcn_global_load_lds(
      (const __attribute__((address_space(1))) void*)g,
      (__attribute__((address_space(3))) void*)l, 16, 0, 0);
}

// ---------------------------------------------------------------------------
// proj tile: C[mt*128..][nt*128..] = A[128][512] . W[128][512]^T + bias  (bf16 out)
// ---------------------------------------------------------------------------
__device__ void proj_tile(const float* __restrict__ A, const float* __restrict__ W,
                          const float* __restrict__ bias, __bf16* __restrict__ C,
                          int mt, int nt, __bf16* As, __bf16* Bs)
{
  const int tid  = threadIdx.x;
  const int r = tid & 127, half = tid >> 7;
  const int lane = tid & 63, wv = tid >> 6;
  const int wm = wv >> 1, wn = wv & 1;

  const float* arow = A + (size_t)(mt * 128 + r) * 512 + half * 32;
  const float* wrow = W + (size_t)(nt * 128 + r) * 512 + half * 32;

  f32x4 acc[4][4] = {};

  for (int k0 = 0; k0 < 512; k0 += 64) {
#pragma unroll
    for (int s = 0; s < 4; ++s) {
      f32x4 a0 = *(const f32x4*)(arow + k0 + s * 8);
      f32x4 a1 = *(const f32x4*)(arow + k0 + s * 8 + 4);
      f32x4 w0 = *(const f32x4*)(wrow + k0 + s * 8);
      f32x4 w1 = *(const f32x4*)(wrow + k0 + s * 8 + 4);
      bf16x8 za, zw;
#pragma unroll
      for (int j = 0; j < 4; ++j) {
        za[j] = (__bf16)a0[j]; za[4 + j] = (__bf16)a1[j];
        zw[j] = (__bf16)w0[j]; zw[4 + j] = (__bf16)w1[j];
      }
      const int kk = half * 32 + s * 8;
      *(bf16x8*)&As[swz64(r, kk)] = za;
      *(bf16x8*)&Bs[swz64(r, kk)] = zw;
    }
    __syncthreads();
#pragma unroll
    for (int kk = 0; kk < 2; ++kk) {
      bf16x8 af[4], bfr[4];
#pragma unroll
      for (int i = 0; i < 4; ++i) {
        af[i]  = *(const bf16x8*)&As[swz64(wm * 64 + i * 16 + (lane & 15), kk * 32 + (lane >> 4) * 8)];
        bfr[i] = *(const bf16x8*)&Bs[swz64(wn * 64 + i * 16 + (lane & 15), kk * 32 + (lane >> 4) * 8)];
      }
#pragma unroll
      for (int mi = 0; mi < 4; ++mi)
#pragma unroll
        for (int ni = 0; ni < 4; ++ni)
          acc[mi][ni] = __builtin_amdgcn_mfma_f32_16x16x32_bf16(af[mi], bfr[ni], acc[mi][ni], 0, 0, 0);
    }
    __syncthreads();
  }

  const int rowbase = mt * 128 + wm * 64;
  const int colbase = nt * 128 + wn * 64;
#pragma unroll
  for (int ni = 0; ni < 4; ++ni) {
    const int col = colbase + ni * 16 + (lane & 15);
    const float bb = bias[col];
#pragma unroll
    for (int mi = 0; mi < 4; ++mi) {
      const int row = rowbase + mi * 16 + (lane >> 4) * 4;
#pragma unroll
      for (int rg = 0; rg < 4; ++rg)
        C[(size_t)(row + rg) * 640 + col] = (__bf16)(acc[mi][ni][rg] + bb);
    }
  }
}

// ---------------------------------------------------------------------------
// prep: blocks 0..39 enc-proj, 40..49 pred-proj, 50..369 out_w conversion.
// zpath=1: Wb blocked [nb(4)][kt(20)][256x32 swz32].
// zpath=0: Wb blocked [nb(8)][kt(10)][128x64 swz64]  (fallback layout).
// ---------------------------------------------------------------------------
__global__ __launch_bounds__(256) void prep_kernel(
    const float* __restrict__ enc,  const float* __restrict__ enc_w,  const float* __restrict__ enc_b,
    const float* __restrict__ pred, const float* __restrict__ pred_w, const float* __restrict__ pred_b,
    const float* __restrict__ out_w,
    __bf16* __restrict__ E, __bf16* __restrict__ P, __bf16* __restrict__ Wb, int zpath)
{
  __shared__ __align__(16) __bf16 As[128 * 64];
  __shared__ __align__(16) __bf16 Bs[128 * 64];
  const int bid = blockIdx.x;
  if (bid < 40) {
    proj_tile(enc, enc_w, enc_b, E, bid / 5, bid % 5, As, Bs);
  } else if (bid < 50) {
    proj_tile(pred, pred_w, pred_b, P, (bid - 40) / 5, (bid - 40) % 5, As, Bs);
  } else {
    const int gid = (bid - 50) * 256 + threadIdx.x;  // 81920 total (1024*80)
    const int v  = gid / 80;
    const int j8 = gid % 80;
    f32x4 w0 = *(const f32x4*)(out_w + (size_t)v * 640 + j8 * 8);
    f32x4 w1 = *(const f32x4*)(out_w + (size_t)v * 640 + j8 * 8 + 4);
    bf16x8 z;
#pragma unroll
    for (int j = 0; j < 4; ++j) { z[j] = (__bf16)w0[j]; z[4 + j] = (__bf16)w1[j]; }
    if (zpath) {
      const int nb = v >> 8, rr = v & 255;
      const int kt = j8 >> 2;
      *(bf16x8*)(Wb + ((size_t)(nb * 20 + kt) << 13) + swz32(rr, (j8 & 3) * 8)) = z;
    } else {
      const int nb = v >> 7, rr = v & 127;
      const int kb = j8 >> 3, kk = (j8 & 7) * 8;
      *(bf16x8*)(Wb + ((size_t)(nb * 10 + kb) << 13) + swz64(rr, kk)) = z;
    }
  }
}

// ---------------------------------------------------------------------------
// zprod: Z[mt][kt][8192] = tanh(E+P), M-tile mt (256 rows), K-tile kt (32 cols),
// written pre-swizzled (swz32) with LINEAR stores; source index inverted
// (swizzle is an involution).  grid = 256*20.
// ---------------------------------------------------------------------------
__global__ __launch_bounds__(256) void zprod_kernel(
    const __bf16* __restrict__ E, const __bf16* __restrict__ P,
    __bf16* __restrict__ Z)
{
  const int bid = blockIdx.x;
  const int mt = bid / 20, kt = bid % 20;
  const int row0 = mt << 8;
  const int b  = row0 >> 14;
  const int t0 = (row0 >> 6) & 255;
  __bf16* zdst = Z + ((size_t)bid << 13);

#pragma unroll
  for (int c = 0; c < 4; ++c) {
    const int o = c * 2048 + threadIdx.x * 8;    // linear offset in 8192-elem tile
    const int r = o >> 5;                        // row 0..255
    const int cc = (o >> 3) & 3;                 // stored 16B chunk
    const int k = kt * 32 + ((cc ^ ((r >> 2) & 3)) << 3);  // original k (inverse swz32)
    const __bf16* ep = E + (size_t)((b << 8) + t0 + (r >> 6)) * 640 + k;
    const __bf16* pp = P + (size_t)((b << 6) + (r & 63)) * 640 + k;
    bf16x8 e8 = *(const bf16x8*)ep;
    bf16x8 p8 = *(const bf16x8*)pp;
    bf16x8 z;
#pragma unroll
    for (int j = 0; j < 8; ++j)
      z[j] = (__bf16)fast_tanh((float)e8[j] + (float)p8[j]);
    *(bf16x8*)&zdst[o] = z;
  }
}

// ---------------------------------------------------------------------------
// main (Z-path): pure bf16 GEMM with 4-slot LDS ring + counted vmcnt (T3+T4).
// Tile 256(M) x 256(N), BK=32, 20 K-tiles, 512 thr = 8 waves (2M x 4N),
// wave-tile 128x64.  Per iter: stage(t+3) [4 gload_lds/wave], ds_read 12
// frags of tile t, 32 MFMA, vmcnt(8) (2 tiles stay in flight), barrier.
// Ring slot (t+3)&3 was last read at iter t-1 -> clobber-safe.
// Grid 1024 = 256 mt x 4 nt, bijective XCD swizzle (1024 % 8 == 0).
// ---------------------------------------------------------------------------
__global__ __launch_bounds__(512, 2) void joiner_ring(
    const __bf16* __restrict__ Z, const __bf16* __restrict__ Wb,
    const float* __restrict__ outb, float* __restrict__ out)
{
  __shared__ __align__(16) __bf16 As[4][8192];   // 64 KB (4 ring slots, 256x32)
  __shared__ __align__(16) __bf16 Bs[4][8192];   // 64 KB
  const int wg = blockIdx.x;
  const int bid = (wg & 7) * 128 + (wg >> 3);    // XCD-contiguous chunks
  const int mt = bid >> 2, nt = bid & 3;
  const int tid = threadIdx.x;
  const int lane = tid & 63, wv = tid >> 6;
  const int wm = wv >> 2, wn = wv & 3;           // 2 x 4 wave grid

  const __bf16* zsrc = Z  + ((size_t)(mt * 20) << 13);
  const __bf16* wsrc = Wb + ((size_t)(nt * 20) << 13);

  f32x4 acc[8][4] = {};

  // A frag: row = wm*128 + mi*16 + (lane&15); k-group g = lane>>4.
  // swz32 group s = ((row>>2)&3) is mi-invariant -> hoisted; offsets are imms.
  const int arow_s = ((wm * 128 + (lane & 15)) >> 2) & 3;
  const int brow_s = ((wn * 64  + (lane & 15)) >> 2) & 3;
  const int aoff = (wm * 128 + (lane & 15)) * 32 + (((lane >> 4) ^ arow_s) << 3);
  const int boff = (wn * 64  + (lane & 15)) * 32 + (((lane >> 4) ^ brow_s) << 3);

  auto stage = [&](int t) {
    const int s = t & 3;
    const size_t g = (size_t)t << 13;
#pragma unroll
    for (int c = 0; c < 2; ++c) {
      const int off = c * 4096 + wv * 512;       // elems; lane*8 on global side
      gload_lds16(zsrc + g + off + lane * 8, &As[s][off]);
      gload_lds16(wsrc + g + off + lane * 8, &Bs[s][off]);
    }
  };

  // prologue: 3 tiles in flight, wait first
  stage(0); stage(1); stage(2);
  asm volatile("s_waitcnt vmcnt(8)" ::: "memory");
  __builtin_amdgcn_s_barrier();

#pragma unroll
  for (int t = 0; t < 20; ++t) {
    const int s = t & 3;
    if (t < 17) stage(t + 3);
    __builtin_amdgcn_s_setprio(1);
    bf16x8 bfr[4];
#pragma unroll
    for (int ni = 0; ni < 4; ++ni)
      bfr[ni] = *(const bf16x8*)&Bs[s][boff + ni * 512];
#pragma unroll
    for (int mi = 0; mi < 8; ++mi) {
      bf16x8 af = *(const bf16x8*)&As[s][aoff + mi * 512];
#pragma unroll
      for (int ni = 0; ni < 4; ++ni)
        acc[mi][ni] = __builtin_amdgcn_mfma_f32_16x16x32_bf16(af, bfr[ni], acc[mi][ni], 0, 0, 0);
    }
    __builtin_amdgcn_s_setprio(0);
    if (t < 19) {
      if (t < 17)       asm volatile("s_waitcnt vmcnt(8)" ::: "memory");
      else if (t == 17) asm volatile("s_waitcnt vmcnt(4)" ::: "memory");
      else              asm volatile("s_waitcnt vmcnt(0)" ::: "memory");
      __builtin_amdgcn_s_barrier();
    }
  }

  // epilogue: bias + store
  const int rowbase = (mt << 8) + wm * 128;
  const int colbase = (nt << 8) + wn * 64;
#pragma unroll
  for (int ni = 0; ni < 4; ++ni) {
    const int col = colbase + ni * 16 + (lane & 15);
    const float bb = outb[col];
#pragma unroll
    for (int mi = 0; mi < 8; ++mi) {
      const int row = rowbase + mi * 16 + (lane >> 4) * 4;
#pragma unroll
      for (int rg = 0; rg < 4; ++rg)
        out[(size_t)(row + rg) * 1024 + col] = acc[mi][ni][rg] + bb;
    }
  }
}

// ---------------------------------------------------------------------------
// Fallback (small ws): R5 fused kernel, Wb in [8][10][128x64 swz64] layout.
// ---------------------------------------------------------------------------
__global__ __launch_bounds__(512, 4) void joiner_fused(
    const __bf16* __restrict__ E, const __bf16* __restrict__ P,
    const __bf16* __restrict__ Wb, const float* __restrict__ outb,
    float* __restrict__ out)
{
  __shared__ __align__(16) __bf16 As[8192];
  __shared__ __align__(16) __bf16 Bs[2][16384];
  const int tid = threadIdx.x;
  const int nt = blockIdx.x & 3;
  const int mt = blockIdx.x >> 2;
  const int row0 = mt << 7;
  const int b  = row0 >> 14;
  const int t0 = (row0 >> 6) & 255;
  const int ar = tid & 127, h = tid >> 7;
  const int lane = tid & 63, wv = tid >> 6;
  const int wm = wv >> 2, wn = wv & 3;

  const __bf16* ep = E + (size_t)((b << 8) + t0 + (ar >> 6)) * 640 + h * 16;
  const __bf16* pp = P + (size_t)((b << 6) + (ar & 63)) * 640 + h * 16;

  f32x4 acc[4][4] = {};
  bf16x8 eA[2], pA[2];

  auto stageB2 = [&](int kt, __bf16* dst) {
#pragma unroll
    for (int c = 0; c < 4; ++c) {
      const int blk = nt * 2 + (c >> 1);
      const int inoff = (c & 1) * 4096 + wv * 512;
      gload_lds16(Wb + ((size_t)(blk * 10 + kt) << 13) + inoff + lane * 8,
                  dst + (c >> 1) * 8192 + inoff);
    }
  };
  auto loadEP = [&](int k0) {
#pragma unroll
    for (int c = 0; c < 2; ++c) {
      eA[c] = *(const bf16x8*)(ep + k0 + c * 8);
      pA[c] = *(const bf16x8*)(pp + k0 + c * 8);
    }
  };
  auto writeA = [&]() {
#pragma unroll
    for (int c = 0; c < 2; ++c) {
      bf16x8 z;
#pragma unroll
      for (int j = 0; j < 8; ++j)
        z[j] = (__bf16)fast_tanh((float)eA[c][j] + (float)pA[c][j]);
      *(bf16x8*)&As[swz64(ar, h * 16 + c * 8)] = z;
    }
  };
  auto compute = [&](const __bf16* Bsc) {
#pragma unroll
    for (int kk = 0; kk < 2; ++kk) {
      bf16x8 af[4], bfr[4];
#pragma unroll
      for (int i = 0; i < 4; ++i) {
        af[i]  = *(const bf16x8*)&As[swz64(wm * 64 + i * 16 + (lane & 15), kk * 32 + (lane >> 4) * 8)];
        bfr[i] = *(const bf16x8*)&Bsc[swz64(wn * 64 + i * 16 + (lane & 15), kk * 32 + (lane >> 4) * 8)];
      }
      asm volatile("s_waitcnt lgkmcnt(0)" ::: "memory");
      __builtin_amdgcn_sched_barrier(0);
      __builtin_amdgcn_s_setprio(1);
#pragma unroll
      for (int mi = 0; mi < 4; ++mi)
#pragma unroll
        for (int ni = 0; ni < 4; ++ni)
          acc[mi][ni] = __builtin_amdgcn_mfma_f32_16x16x32_bf16(af[mi], bfr[ni], acc[mi][ni], 0, 0, 0);
      __builtin_amdgcn_s_setprio(0);
    }
  };

  stageB2(0, Bs[0]);
  loadEP(0);
  writeA();
  asm volatile("s_waitcnt vmcnt(0) lgkmcnt(0)" ::: "memory");
  __builtin_amdgcn_s_barrier();

  for (int kt = 0; kt < 9; ++kt) {
    const int cur = kt & 1;
    stageB2(kt + 1, Bs[cur ^ 1]);
    loadEP((kt + 1) << 6);
    compute(Bs[cur]);
    __builtin_amdgcn_s_barrier();
    __builtin_amdgcn_sched_barrier(0);
    writeA();
    asm volatile("s_waitcnt lgkmcnt(0)" ::: "memory");
    __builtin_amdgcn_s_barrier();
  }
  compute(Bs[1]);

  const int rowbase = row0 + wm * 64;
  const int colbase = (nt << 8) + wn * 64;
#pragma unroll
  for (int ni = 0; ni < 4; ++ni) {
    const int col = colbase + ni * 16 + (lane & 15);
    const float bb = outb[col];
#pragma unroll
    for (int mi = 0; mi < 4; ++mi) {
      const int row = rowbase + mi * 16 + (lane >> 4) * 4;
#pragma unroll
      for (int rg = 0; rg < 4; ++rg)
        out[(size_t)(row + rg) * 1024 + col] = acc[mi][ni][rg] + bb;
    }
  }
}

extern "C" void kernel_launch(void* const* d_in, const int* in_sizes, int n_in,
                              void* d_out, int out_size, void* d_ws, size_t ws_size,
                              hipStream_t stream) {
  const float* enc    = (const float*)d_in[0];
  const float* pred   = (const float*)d_in[1];
  const float* enc_w  = (const float*)d_in[2];
  const float* enc_b  = (const float*)d_in[3];
  const float* pred_w = (const float*)d_in[4];
  const float* pred_b = (const float*)d_in[5];
  const float* out_w  = (const float*)d_in[6];
  const float* out_b  = (const float*)d_in[7];
  float* out = (float*)d_out;

  char* ws = (char*)d_ws;
  __bf16* E  = (__bf16*)(ws);                 // 1024*640 bf16
  __bf16* P  = (__bf16*)(ws + 1310720);       //  256*640 bf16
  __bf16* Wb = (__bf16*)(ws + 1638400);       // pre-swizzled out_w blocks
  __bf16* Z  = (__bf16*)(ws + 2949120);       // 256*20*8192 bf16, pre-swizzled

  const int zpath = (ws_size >= (size_t)86835200) ? 1 : 0;

  prep_kernel<<<dim3(370), dim3(256), 0, stream>>>(
      enc, enc_w, enc_b, pred, pred_w, pred_b, out_w, E, P, Wb, zpath);

  if (zpath) {
    zprod_kernel<<<dim3(5120), dim3(256), 0, stream>>>(E, P, Z);
    joiner_ring<<<dim3(1024), dim3(512), 0, stream>>>(Z, Wb, out_b, out);
  } else {
    joiner_fused<<<dim3(2048), dim3(512), 0, stream>>>(E, P, Wb, out_b, out);
  }
}

// Round 8
// 154.525 us; speedup vs baseline: 1.1208x; 1.1208x over previous
//
#include <hip/hip_runtime.h>
#include <cstdint>
#include <cstddef>

// RNNT joiner: logits[b,t,u,v] = sum_j tanh(E[b,t,j]+P[b,u,j]) * out_w[v,j] + out_b[v]
// B=4 T=256 U=64 D=512 J=640 V=1024.  M = 65536 rows (b,t,u), N=1024, K=640.
//
// ws layout (Z-path):
//   E  : bf16 [1024][640]                  @ 0          (1,310,720 B)
//   P  : bf16 [ 256][640]                  @ 1,310,720  (  327,680 B)
//   Wb : bf16 [nt=4][kt=10][half=2][8192]  @ 1,638,400  (1,310,720 B)  pre-swizzled 128x64 half-tiles
//   Z  : bf16 [mt=256][kt=10][half=2][8192]@ 2,949,120  (83,886,080 B) pre-swizzled 128x64 half-tiles
// total 86,835,200 B.  ws_size smaller -> fused fallback (R5 structure, [8][10] 128x64 Wb).

typedef __attribute__((ext_vector_type(8))) __bf16 bf16x8;
typedef __attribute__((ext_vector_type(4))) float f32x4;

// XOR swizzle within a [128][64] bf16 half-tile (row stride 128B).
__device__ __forceinline__ int swz64(int row, int kElem) {
  return (row << 6) + (kElem ^ ((row & 7) << 3));
}

__device__ __forceinline__ float fast_tanh(float x) {
  float e = __builtin_amdgcn_exp2f(x * 2.88539008177793f);  // e^(2x)
  return 1.0f - 2.0f * __builtin_amdgcn_rcpf(e + 1.0f);
}

__device__ __forceinline__ void gload_lds16(const void* g, void* l) {
  __builtin_amdgcn_global_load_lds(
      (const __attribute__((address_space(1))) void*)g,
      (__attribute__((address_space(3))) void*)l, 16, 0, 0);
}

// ---------------------------------------------------------------------------
// proj tile: C[mt*128..][nt*128..] = A[128][512] . W[128][512]^T + bias  (bf16 out)
// ---------------------------------------------------------------------------
__device__ void proj_tile(const float* __restrict__ A, const float* __restrict__ W,
                          const float* __restrict__ bias, __bf16* __restrict__ C,
                          int mt, int nt, __bf16* As, __bf16* Bs)
{
  const int tid  = threadIdx.x;
  const int r = tid & 127, half = tid >> 7;
  const int lane = tid & 63, wv = tid >> 6;
  const int wm = wv >> 1, wn = wv & 1;

  const float* arow = A + (size_t)(mt * 128 + r) * 512 + half * 32;
  const float* wrow = W + (size_t)(nt * 128 + r) * 512 + half * 32;

  f32x4 acc[4][4] = {};

  for (int k0 = 0; k0 < 512; k0 += 64) {
#pragma unroll
    for (int s = 0; s < 4; ++s) {
      f32x4 a0 = *(const f32x4*)(arow + k0 + s * 8);
      f32x4 a1 = *(const f32x4*)(arow + k0 + s * 8 + 4);
      f32x4 w0 = *(const f32x4*)(wrow + k0 + s * 8);
      f32x4 w1 = *(const f32x4*)(wrow + k0 + s * 8 + 4);
      bf16x8 za, zw;
#pragma unroll
      for (int j = 0; j < 4; ++j) {
        za[j] = (__bf16)a0[j]; za[4 + j] = (__bf16)a1[j];
        zw[j] = (__bf16)w0[j]; zw[4 + j] = (__bf16)w1[j];
      }
      const int kk = half * 32 + s * 8;
      *(bf16x8*)&As[swz64(r, kk)] = za;
      *(bf16x8*)&Bs[swz64(r, kk)] = zw;
    }
    __syncthreads();
#pragma unroll
    for (int kk = 0; kk < 2; ++kk) {
      bf16x8 af[4], bfr[4];
#pragma unroll
      for (int i = 0; i < 4; ++i) {
        af[i]  = *(const bf16x8*)&As[swz64(wm * 64 + i * 16 + (lane & 15), kk * 32 + (lane >> 4) * 8)];
        bfr[i] = *(const bf16x8*)&Bs[swz64(wn * 64 + i * 16 + (lane & 15), kk * 32 + (lane >> 4) * 8)];
      }
#pragma unroll
      for (int mi = 0; mi < 4; ++mi)
#pragma unroll
        for (int ni = 0; ni < 4; ++ni)
          acc[mi][ni] = __builtin_amdgcn_mfma_f32_16x16x32_bf16(af[mi], bfr[ni], acc[mi][ni], 0, 0, 0);
    }
    __syncthreads();
  }

  const int rowbase = mt * 128 + wm * 64;
  const int colbase = nt * 128 + wn * 64;
#pragma unroll
  for (int ni = 0; ni < 4; ++ni) {
    const int col = colbase + ni * 16 + (lane & 15);
    const float bb = bias[col];
#pragma unroll
    for (int mi = 0; mi < 4; ++mi) {
      const int row = rowbase + mi * 16 + (lane >> 4) * 4;
#pragma unroll
      for (int rg = 0; rg < 4; ++rg)
        C[(size_t)(row + rg) * 640 + col] = (__bf16)(acc[mi][ni][rg] + bb);
    }
  }
}

// ---------------------------------------------------------------------------
// prep: blocks 0..39 enc-proj, 40..49 pred-proj, 50..369 out_w conversion.
// zpath=1: Wb [nt(4)][kt(10)][half(2)][128x64 swz64].
// zpath=0: Wb [nb(8)][kt(10)][128x64 swz64]  (fallback layout).
// ---------------------------------------------------------------------------
__global__ __launch_bounds__(256) void prep_kernel(
    const float* __restrict__ enc,  const float* __restrict__ enc_w,  const float* __restrict__ enc_b,
    const float* __restrict__ pred, const float* __restrict__ pred_w, const float* __restrict__ pred_b,
    const float* __restrict__ out_w,
    __bf16* __restrict__ E, __bf16* __restrict__ P, __bf16* __restrict__ Wb, int zpath)
{
  __shared__ __align__(16) __bf16 As[128 * 64];
  __shared__ __align__(16) __bf16 Bs[128 * 64];
  const int bid = blockIdx.x;
  if (bid < 40) {
    proj_tile(enc, enc_w, enc_b, E, bid / 5, bid % 5, As, Bs);
  } else if (bid < 50) {
    proj_tile(pred, pred_w, pred_b, P, (bid - 40) / 5, (bid - 40) % 5, As, Bs);
  } else {
    const int gid = (bid - 50) * 256 + threadIdx.x;  // 81920 total (1024*80)
    const int v  = gid / 80;
    const int j8 = gid % 80;
    f32x4 w0 = *(const f32x4*)(out_w + (size_t)v * 640 + j8 * 8);
    f32x4 w1 = *(const f32x4*)(out_w + (size_t)v * 640 + j8 * 8 + 4);
    bf16x8 z;
#pragma unroll
    for (int j = 0; j < 4; ++j) { z[j] = (__bf16)w0[j]; z[4 + j] = (__bf16)w1[j]; }
    if (zpath) {
      const int nt = v >> 8, vv = v & 255;
      const int half = vv >> 7, rr = vv & 127;
      const int kt = j8 >> 3, kk = (j8 & 7) * 8;
      *(bf16x8*)(Wb + (((size_t)(nt * 10 + kt) * 2 + half) << 13) + swz64(rr, kk)) = z;
    } else {
      const int nb = v >> 7, rr = v & 127;
      const int kb = j8 >> 3, kk = (j8 & 7) * 8;
      *(bf16x8*)(Wb + ((size_t)(nb * 10 + kb) << 13) + swz64(rr, kk)) = z;
    }
  }
}

// ---------------------------------------------------------------------------
// zprod: Z[mt][kt][half][8192] = tanh(E+P), pre-swizzled half-tiles, LINEAR
// stores (swizzle inverted at source index; XOR swizzle is an involution).
// grid = 2560 (mt*10+kt), 256 thr, 32KB per block.
// ---------------------------------------------------------------------------
__global__ __launch_bounds__(256) void zprod_kernel(
    const __bf16* __restrict__ E, const __bf16* __restrict__ P,
    __bf16* __restrict__ Z)
{
  const int bid = blockIdx.x;
  const int mt = bid / 10, kt = bid % 10;
  __bf16* zdst = Z + ((size_t)bid << 14);      // 16384 elems per (mt,kt)

#pragma unroll
  for (int c = 0; c < 8; ++c) {
    const int o = c * 2048 + threadIdx.x * 8;  // linear offset in 16K-elem block
    const int half = o >> 13, oo = o & 8191;
    const int rr = oo >> 6;
    const int r = half * 128 + rr;             // tile row 0..255
    const int k = kt * 64 + ((oo & 63) ^ ((rr & 7) << 3));
    const int grow = mt * 256 + r;             // global M-row
    const __bf16* ep = E + (size_t)(grow >> 6) * 640 + k;                      // b*256+t
    const __bf16* pp = P + (size_t)(((grow >> 14) << 6) | (grow & 63)) * 640 + k; // b*64+u
    bf16x8 e8 = *(const bf16x8*)ep;
    bf16x8 p8 = *(const bf16x8*)pp;
    bf16x8 z;
#pragma unroll
    for (int j = 0; j < 8; ++j)
      z[j] = (__bf16)fast_tanh((float)e8[j] + (float)p8[j]);
    *(bf16x8*)&zdst[o] = z;
  }
}

// ---------------------------------------------------------------------------
// main (Z-path): m201-style 8-phase GEMM.  Tile 256x256, BK=64, 10 K-tiles,
// 512 thr = 8 waves (2M x 4N), wave-tile 128x64 with INTERLEAVED frags:
// A-frag f at rows f*32+wm*16, B-frag g at cols g*64+wn*16 -> every wave's
// phase-q quadrant touches the same half-tiles: P0={A0,B0} P1={B1} P2={A1}
// P3={regs}.  Half-tile stage stream [A0,B0,B1,A1] runs 7 phases ahead;
// vmcnt(6) once per K-tile (counted, never drain except last tile).
// LDS 128KB (2 dbuf x 2 half x 16KB x {A,B}).  Grid 1024, XCD-swizzled.
// ---------------------------------------------------------------------------
__global__ __launch_bounds__(512, 2) void joiner_8p(
    const __bf16* __restrict__ Z, const __bf16* __restrict__ Wb,
    const float* __restrict__ outb, float* __restrict__ out)
{
  __shared__ __align__(16) __bf16 As[2][2][8192];   // [dbuf][half][128x64]
  __shared__ __align__(16) __bf16 Bs[2][2][8192];
  const int wg = blockIdx.x;
  const int bid = (wg & 7) * 128 + (wg >> 3);       // XCD-contiguous chunks
  const int mt = bid >> 2, nt = bid & 3;
  const int tid = threadIdx.x;
  const int lane = tid & 63, wv = tid >> 6;
  const int wm = wv >> 2, wn = wv & 3;              // 2 x 4 wave grid

  const int rb  = wm * 16 + (lane & 15);            // A row base within 32-row group
  const int cb  = wn * 16 + (lane & 15);            // B col base within 64-col group
  const int kb8 = (lane >> 4) * 8;

  const __bf16* zsrc = Z  + ((size_t)(mt * 20) << 13);  // [10][2][8192]
  const __bf16* wsrc = Wb + ((size_t)(nt * 20) << 13);

  f32x4 acc[8][4] = {};

  auto stA = [&](int kt, int half) {
    __bf16* dst = &As[kt & 1][half][wv * 512];
    const __bf16* src = zsrc + (((size_t)kt * 2 + half) << 13) + wv * 512 + lane * 8;
    gload_lds16(src, dst);
    gload_lds16(src + 4096, dst + 4096);
  };
  auto stB = [&](int kt, int half) {
    __bf16* dst = &Bs[kt & 1][half][wv * 512];
    const __bf16* src = wsrc + (((size_t)kt * 2 + half) << 13) + wv * 512 + lane * 8;
    gload_lds16(src, dst);
    gload_lds16(src + 4096, dst + 4096);
  };

  // ---- prologue: stage stream s=0..6 = K0{A0,B0,B1,A1} K1{A0,B0,B1} ----
  stA(0, 0); stB(0, 0); stB(0, 1); stA(0, 1);
  stA(1, 0); stB(1, 0); stB(1, 1);
  asm volatile("s_waitcnt vmcnt(6)" ::: "memory");  // K0 fully visible
  __builtin_amdgcn_s_barrier();

#pragma unroll
  for (int k = 0; k < 10; ++k) {
    const int d = k & 1;
    const __bf16* A0 = &As[d][0][0];
    const __bf16* A1 = &As[d][1][0];
    const __bf16* B0 = &Bs[d][0][0];
    const __bf16* B1 = &Bs[d][1][0];
    bf16x8 afl[4][2], afh[4][2], bl[2][2], bh[2][2];

    // ===== P0: reads A0,B0; stage A1(k+1); vmcnt(6); MFMA f0-3 x g0-1 =====
#pragma unroll
    for (int f = 0; f < 4; ++f)
#pragma unroll
      for (int kk = 0; kk < 2; ++kk)
        afl[f][kk] = *(const bf16x8*)&A0[swz64(f * 32 + rb, kk * 32 + kb8)];
#pragma unroll
    for (int g = 0; g < 2; ++g)
#pragma unroll
      for (int kk = 0; kk < 2; ++kk)
        bl[g][kk] = *(const bf16x8*)&B0[swz64(g * 64 + cb, kk * 32 + kb8)];
    if (k < 9) stA(k + 1, 1);
    if (k == 9) asm volatile("s_waitcnt vmcnt(0)" ::: "memory");
    else        asm volatile("s_waitcnt vmcnt(6)" ::: "memory");
    __builtin_amdgcn_s_barrier();
    asm volatile("s_waitcnt lgkmcnt(0)" ::: "memory");
    __builtin_amdgcn_sched_barrier(0);
    __builtin_amdgcn_s_setprio(1);
#pragma unroll
    for (int kk = 0; kk < 2; ++kk)
#pragma unroll
      for (int f = 0; f < 4; ++f)
#pragma unroll
        for (int g = 0; g < 2; ++g)
          acc[f][g] = __builtin_amdgcn_mfma_f32_16x16x32_bf16(afl[f][kk], bl[g][kk], acc[f][g], 0, 0, 0);
    __builtin_amdgcn_s_setprio(0);
    __builtin_amdgcn_s_barrier();

    // ===== P1: reads B1; stage A0(k+2); MFMA f0-3 x g2-3 =====
#pragma unroll
    for (int g = 0; g < 2; ++g)
#pragma unroll
      for (int kk = 0; kk < 2; ++kk)
        bh[g][kk] = *(const bf16x8*)&B1[swz64(g * 64 + cb, kk * 32 + kb8)];
    if (k < 8) stA(k + 2, 0);
    __builtin_amdgcn_s_barrier();
    asm volatile("s_waitcnt lgkmcnt(0)" ::: "memory");
    __builtin_amdgcn_sched_barrier(0);
    __builtin_amdgcn_s_setprio(1);
#pragma unroll
    for (int kk = 0; kk < 2; ++kk)
#pragma unroll
      for (int f = 0; f < 4; ++f)
#pragma unroll
        for (int g = 0; g < 2; ++g)
          acc[f][2 + g] = __builtin_amdgcn_mfma_f32_16x16x32_bf16(afl[f][kk], bh[g][kk], acc[f][2 + g], 0, 0, 0);
    __builtin_amdgcn_s_setprio(0);
    __builtin_amdgcn_s_barrier();

    // ===== P2: reads A1; stage B0(k+2); MFMA f4-7 x g2-3 =====
#pragma unroll
    for (int f = 0; f < 4; ++f)
#pragma unroll
      for (int kk = 0; kk < 2; ++kk)
        afh[f][kk] = *(const bf16x8*)&A1[swz64(f * 32 + rb, kk * 32 + kb8)];
    if (k < 8) stB(k + 2, 0);
    __builtin_amdgcn_s_barrier();
    asm volatile("s_waitcnt lgkmcnt(0)" ::: "memory");
    __builtin_amdgcn_sched_barrier(0);
    __builtin_amdgcn_s_setprio(1);
#pragma unroll
    for (int kk = 0; kk < 2; ++kk)
#pragma unroll
      for (int f = 0; f < 4; ++f)
#pragma unroll
        for (int g = 0; g < 2; ++g)
          acc[4 + f][2 + g] = __builtin_amdgcn_mfma_f32_16x16x32_bf16(afh[f][kk], bh[g][kk], acc[4 + f][2 + g], 0, 0, 0);
    __builtin_amdgcn_s_setprio(0);
    __builtin_amdgcn_s_barrier();

    // ===== P3: register-only; stage B1(k+2); MFMA f4-7 x g0-1 =====
    if (k < 8) stB(k + 2, 1);
    __builtin_amdgcn_s_setprio(1);
#pragma unroll
    for (int kk = 0; kk < 2; ++kk)
#pragma unroll
      for (int f = 0; f < 4; ++f)
#pragma unroll
        for (int g = 0; g < 2; ++g)
          acc[4 + f][g] = __builtin_amdgcn_mfma_f32_16x16x32_bf16(afh[f][kk], bl[g][kk], acc[4 + f][g], 0, 0, 0);
    __builtin_amdgcn_s_setprio(0);
  }

  // ---- epilogue: bias + store ----
  const int rowbase = (mt << 8) + wm * 16 + (lane >> 4) * 4;
  const int colbase = (nt << 8) + wn * 16 + (lane & 15);
#pragma unroll
  for (int g = 0; g < 4; ++g) {
    const int col = colbase + g * 64;
    const float bb = outb[col];
#pragma unroll
    for (int f = 0; f < 8; ++f) {
      const int row = rowbase + f * 32;
#pragma unroll
      for (int rg = 0; rg < 4; ++rg)
        out[(size_t)(row + rg) * 1024 + col] = acc[f][g][rg] + bb;
    }
  }
}

// ---------------------------------------------------------------------------
// Fallback (small ws): R5 fused kernel, Wb in [8][10][128x64 swz64] layout.
// ---------------------------------------------------------------------------
__global__ __launch_bounds__(512, 4) void joiner_fused(
    const __bf16* __restrict__ E, const __bf16* __restrict__ P,
    const __bf16* __restrict__ Wb, const float* __restrict__ outb,
    float* __restrict__ out)
{
  __shared__ __align__(16) __bf16 As[8192];
  __shared__ __align__(16) __bf16 Bs[2][16384];
  const int tid = threadIdx.x;
  const int nt = blockIdx.x & 3;
  const int mt = blockIdx.x >> 2;
  const int row0 = mt << 7;
  const int b  = row0 >> 14;
  const int t0 = (row0 >> 6) & 255;
  const int ar = tid & 127, h = tid >> 7;
  const int lane = tid & 63, wv = tid >> 6;
  const int wm = wv >> 2, wn = wv & 3;

  const __bf16* ep = E + (size_t)((b << 8) + t0 + (ar >> 6)) * 640 + h * 16;
  const __bf16* pp = P + (size_t)((b << 6) + (ar & 63)) * 640 + h * 16;

  f32x4 acc[4][4] = {};
  bf16x8 eA[2], pA[2];

  auto stageB2 = [&](int kt, __bf16* dst) {
#pragma unroll
    for (int c = 0; c < 4; ++c) {
      const int blk = nt * 2 + (c >> 1);
      const int inoff = (c & 1) * 4096 + wv * 512;
      gload_lds16(Wb + ((size_t)(blk * 10 + kt) << 13) + inoff + lane * 8,
                  dst + (c >> 1) * 8192 + inoff);
    }
  };
  auto loadEP = [&](int k0) {
#pragma unroll
    for (int c = 0; c < 2; ++c) {
      eA[c] = *(const bf16x8*)(ep + k0 + c * 8);
      pA[c] = *(const bf16x8*)(pp + k0 + c * 8);
    }
  };
  auto writeA = [&]() {
#pragma unroll
    for (int c = 0; c < 2; ++c) {
      bf16x8 z;
#pragma unroll
      for (int j = 0; j < 8; ++j)
        z[j] = (__bf16)fast_tanh((float)eA[c][j] + (float)pA[c][j]);
      *(bf16x8*)&As[swz64(ar, h * 16 + c * 8)] = z;
    }
  };
  auto compute = [&](const __bf16* Bsc) {
#pragma unroll
    for (int kk = 0; kk < 2; ++kk) {
      bf16x8 af[4], bfr[4];
#pragma unroll
      for (int i = 0; i < 4; ++i) {
        af[i]  = *(const bf16x8*)&As[swz64(wm * 64 + i * 16 + (lane & 15), kk * 32 + (lane >> 4) * 8)];
        bfr[i] = *(const bf16x8*)&Bsc[swz64(wn * 64 + i * 16 + (lane & 15), kk * 32 + (lane >> 4) * 8)];
      }
      asm volatile("s_waitcnt lgkmcnt(0)" ::: "memory");
      __builtin_amdgcn_sched_barrier(0);
      __builtin_amdgcn_s_setprio(1);
#pragma unroll
      for (int mi = 0; mi < 4; ++mi)
#pragma unroll
        for (int ni = 0; ni < 4; ++ni)
          acc[mi][ni] = __builtin_amdgcn_mfma_f32_16x16x32_bf16(af[mi], bfr[ni], acc[mi][ni], 0, 0, 0);
      __builtin_amdgcn_s_setprio(0);
    }
  };

  stageB2(0, Bs[0]);
  loadEP(0);
  writeA();
  asm volatile("s_waitcnt vmcnt(0) lgkmcnt(0)" ::: "memory");
  __builtin_amdgcn_s_barrier();

  for (int kt = 0; kt < 9; ++kt) {
    const int cur = kt & 1;
    stageB2(kt + 1, Bs[cur ^ 1]);
    loadEP((kt + 1) << 6);
    compute(Bs[cur]);
    __builtin_amdgcn_s_barrier();
    __builtin_amdgcn_sched_barrier(0);
    writeA();
    asm volatile("s_waitcnt lgkmcnt(0)" ::: "memory");
    __builtin_amdgcn_s_barrier();
  }
  compute(Bs[1]);

  const int rowbase = row0 + wm * 64;
  const int colbase = (nt << 8) + wn * 64;
#pragma unroll
  for (int ni = 0; ni < 4; ++ni) {
    const int col = colbase + ni * 16 + (lane & 15);
    const float bb = outb[col];
#pragma unroll
    for (int mi = 0; mi < 4; ++mi) {
      const int row = rowbase + mi * 16 + (lane >> 4) * 4;
#pragma unroll
      for (int rg = 0; rg < 4; ++rg)
        out[(size_t)(row + rg) * 1024 + col] = acc[mi][ni][rg] + bb;
    }
  }
}

extern "C" void kernel_launch(void* const* d_in, const int* in_sizes, int n_in,
                              void* d_out, int out_size, void* d_ws, size_t ws_size,
                              hipStream_t stream) {
  const float* enc    = (const float*)d_in[0];
  const float* pred   = (const float*)d_in[1];
  const float* enc_w  = (const float*)d_in[2];
  const float* enc_b  = (const float*)d_in[3];
  const float* pred_w = (const float*)d_in[4];
  const float* pred_b = (const float*)d_in[5];
  const float* out_w  = (const float*)d_in[6];
  const float* out_b  = (const float*)d_in[7];
  float* out = (float*)d_out;

  char* ws = (char*)d_ws;
  __bf16* E  = (__bf16*)(ws);                 // 1024*640 bf16
  __bf16* P  = (__bf16*)(ws + 1310720);       //  256*640 bf16
  __bf16* Wb = (__bf16*)(ws + 1638400);       // pre-swizzled out_w half-tiles
  __bf16* Z  = (__bf16*)(ws + 2949120);       // 256*10*2*8192 bf16, pre-swizzled

  const int zpath = (ws_size >= (size_t)86835200) ? 1 : 0;

  prep_kernel<<<dim3(370), dim3(256), 0, stream>>>(
      enc, enc_w, enc_b, pred, pred_w, pred_b, out_w, E, P, Wb, zpath);

  if (zpath) {
    zprod_kernel<<<dim3(2560), dim3(256), 0, stream>>>(E, P, Z);
    joiner_8p<<<dim3(1024), dim3(512), 0, stream>>>(Z, Wb, out_b, out);
  } else {
    joiner_fused<<<dim3(2048), dim3(512), 0, stream>>>(E, P, Wb, out_b, out);
  }
}